// Round 1
// baseline (567.077 us; speedup 1.0000x reference)
//
#include <hip/hip_runtime.h>
#include <cfloat>
#include <cstdint>

// Problem constants (YOLOv8 640x640 head)
#define NB 64
#define NG 32
#define NC 80
#define NA 8400
#define KTOP 13

// ---------------------------------------------------------------------------
// Phase A: per (b,a) -> decode pred box, softmax, IoU vs all 32 GTs, align
// Writes: align (B,G,A) fp32, inside32 (B,A), bestg (B,A), zeros mask32 (B,A)
// ---------------------------------------------------------------------------
__global__ __launch_bounds__(256) void phaseA(
    const float* __restrict__ preds,          // (B, 84, A)
    const float* __restrict__ gt_bboxes,      // (B, G, 4) xyxy
    const int*   __restrict__ gt_classes,     // (B, G)
    const float* __restrict__ anchor_points,  // (A, 2)
    float*       __restrict__ align,          // (B,G,A)
    unsigned*    __restrict__ mask32,         // (B,A) topk scatter (zeroed here)
    unsigned*    __restrict__ inside32,       // (B,A)
    int*         __restrict__ bestg,          // (B,A)
    float*       __restrict__ out_sum)        // scalar, zeroed here
{
    __shared__ float sx1[NG], sy1[NG], sx2[NG], sy2[NG], sarea[NG];
    __shared__ int   scls[NG];

    const int tid = threadIdx.x;
    const int b   = blockIdx.y;
    const int a   = blockIdx.x * 256 + tid;

    if (tid < NG) {
        const float* gb = gt_bboxes + ((size_t)b * NG + tid) * 4;
        float x1 = gb[0], y1 = gb[1], x2 = gb[2], y2 = gb[3];
        sx1[tid] = x1; sy1[tid] = y1; sx2[tid] = x2; sy2[tid] = y2;
        sarea[tid] = (x2 - x1) * (y2 - y1);
        scls[tid]  = gt_classes[b * NG + tid];
    }
    if (b == 0 && a == 0) out_sum[0] = 0.0f;
    __syncthreads();
    if (a >= NA) return;

    const float ax = anchor_points[a * 2 + 0];
    const float ay = anchor_points[a * 2 + 1];

    const float* db = preds + (size_t)b * (4 + NC) * NA + a;  // dist base
    const float l  = db[0];
    const float t  = db[(size_t)1 * NA];
    const float r  = db[(size_t)2 * NA];
    const float bo = db[(size_t)3 * NA];
    const float x1 = ax - l, y1 = ay - t, x2 = ax + r, y2 = ay + bo;
    const float area_a = (x2 - x1) * (y2 - y1);

    // softmax over 80 classes: max pass, then sum-exp pass (matches jax.nn.softmax)
    const float* cb = db + (size_t)4 * NA;
    float mx = -FLT_MAX;
    for (int c = 0; c < NC; ++c) mx = fmaxf(mx, cb[(size_t)c * NA]);
    float denom = 0.0f;
    for (int c = 0; c < NC; ++c) denom += expf(cb[(size_t)c * NA] - mx);

    unsigned inside = 0u;
    int   bg   = 0;
    float biou = -1.0f;   // iou >= 0 so g=0 always considered; strict > keeps first max (jnp.argmax)

    float* arow = align + ((size_t)b * NG) * NA + a;
    for (int g = 0; g < NG; ++g) {
        const float bx1 = sx1[g], by1 = sy1[g], bx2 = sx2[g], by2 = sy2[g];
        const float ltx = fmaxf(x1, bx1), lty = fmaxf(y1, by1);
        const float rbx = fminf(x2, bx2), rby = fminf(y2, by2);
        const float w = fmaxf(rbx - ltx, 0.0f);
        const float h = fmaxf(rby - lty, 0.0f);
        const float inter = w * h;
        const float iou = inter / (area_a + sarea[g] - inter + 1e-7f);
        if (iou > biou) { biou = iou; bg = g; }
        const float cv = expf(cb[(size_t)scls[g] * NA] - mx) / denom;
        const float al = sqrtf(fmaxf(iou, 1e-12f)) * sqrtf(fmaxf(cv, 1e-12f));
        arow[(size_t)g * NA] = al;
        const float dmin = fminf(fminf(ax - bx1, ay - by1), fminf(bx2 - ax, by2 - ay));
        if (dmin > 1e-9f) inside |= (1u << g);
    }

    const int i = b * NA + a;
    mask32[i]   = 0u;
    inside32[i] = inside;
    bestg[i]    = bg;
}

// ---------------------------------------------------------------------------
// Phase B: one 64-lane wave per (b,g): top-13 over A anchors of align[b,g,:]
// Scatter: atomicOr bit g into mask32[b, winner_anchor]
// ---------------------------------------------------------------------------
__global__ __launch_bounds__(256) void phaseB(
    const float* __restrict__ align,   // (B,G,A)
    unsigned*    __restrict__ mask32)  // (B,A)
{
    const int lane = threadIdx.x & 63;
    const int w    = (blockIdx.x * 256 + threadIdx.x) >> 6;  // 0 .. B*G-1
    const int b    = w >> 5;   // / NG
    const int g    = w & 31;   // % NG

    const float* row = align + (size_t)w * NA;

    float v[KTOP];
    int   id[KTOP];
#pragma unroll
    for (int j = 0; j < KTOP; ++j) { v[j] = -FLT_MAX; id[j] = 0x7FFFFFFF; }

    // each lane: local stable top-13 of its strided slice (increasing index order;
    // strict > means equal values keep the earlier index -> matches stable sort)
    for (int a = lane; a < NA; a += 64) {
        const float x = row[a];
        if (x > v[KTOP - 1]) {
            int j = KTOP - 1;
            while (j > 0 && v[j - 1] < x) { v[j] = v[j - 1]; id[j] = id[j - 1]; --j; }
            v[j] = x; id[j] = a;
        }
    }

    // 13 rounds of wave-argmax merge (tie-break: smaller anchor index)
    int p = 0;
    for (int round = 0; round < KTOP; ++round) {
        const float cv = (p < KTOP) ? v[p]  : -FLT_MAX;
        const int   ci = (p < KTOP) ? id[p] : 0x7FFFFFFF;
        float bv = cv;
        int   bi = ci;
#pragma unroll
        for (int off = 32; off > 0; off >>= 1) {
            const float ov = __shfl_xor(bv, off, 64);
            const int   oi = __shfl_xor(bi, off, 64);
            if (ov > bv || (ov == bv && oi < bi)) { bv = ov; bi = oi; }
        }
        if (ci == bi) ++p;  // unique indices across lanes -> exactly one lane pops
        if (lane == 0) atomicOr(&mask32[b * NA + bi], 1u << g);
    }
}

// ---------------------------------------------------------------------------
// Phase C: per (b,a) resolve assignment and write all outputs (as float)
// out layout: tb (B,A,4) | tc (B,A) | ts (B,A) | fg (B,A) | fg_sum (1)
// ---------------------------------------------------------------------------
__global__ __launch_bounds__(256) void phaseC(
    const float*    __restrict__ gt_bboxes,
    const int*      __restrict__ gt_classes,
    const float*    __restrict__ align,     // (B,G,A)
    const unsigned* __restrict__ mask32,
    const unsigned* __restrict__ inside32,
    const int*      __restrict__ bestg,
    float*          __restrict__ out)
{
    const int i = blockIdx.x * 256 + threadIdx.x;
    if (i >= NB * NA) return;
    const int b = i / NA;
    const int a = i - b * NA;

    const unsigned m = mask32[i] & inside32[i];
    const int cnt = __popc(m);

    bool fg;
    int  tgt;
    if (cnt > 1)      { tgt = bestg[i];      fg = true;  }
    else if (cnt == 1){ tgt = __ffs(m) - 1;  fg = true;  }
    else              { tgt = 0;             fg = false; }

    const float f = fg ? 1.0f : 0.0f;
    const float* gb = gt_bboxes + ((size_t)b * NG + tgt) * 4;

    float* tb = out + (size_t)i * 4;
    tb[0] = gb[0] * f;
    tb[1] = gb[1] * f;
    tb[2] = gb[2] * f;
    tb[3] = gb[3] * f;

    const size_t BA = (size_t)NB * NA;
    out[BA * 4 + i] = fg ? (float)gt_classes[b * NG + tgt] : 0.0f;
    out[BA * 5 + i] = fg ? align[((size_t)b * NG + tgt) * NA + a] : 0.0f;
    out[BA * 6 + i] = f;

    // exact integer-valued fp32 accumulation of fg.sum()
    const unsigned long long ball = __ballot(fg);
    if ((threadIdx.x & 63) == 0)
        atomicAdd(&out[BA * 7], (float)__popcll(ball));
}

// ---------------------------------------------------------------------------
extern "C" void kernel_launch(void* const* d_in, const int* in_sizes, int n_in,
                              void* d_out, int out_size, void* d_ws, size_t ws_size,
                              hipStream_t stream) {
    const float* preds         = (const float*)d_in[0];
    const float* gt_bboxes     = (const float*)d_in[1];
    const int*   gt_classes    = (const int*)  d_in[2];
    const float* anchor_points = (const float*)d_in[3];
    // d_in[4] stride_tensor: unused by the reference math

    float* out = (float*)d_out;

    // workspace carve-up: align (B,G,A) fp32 + 3x (B,A) u32
    char* ws = (char*)d_ws;
    float*    align_ws = (float*)ws;
    size_t    off = (size_t)NB * NG * NA * sizeof(float);
    unsigned* mask32   = (unsigned*)(ws + off);  off += (size_t)NB * NA * sizeof(unsigned);
    unsigned* inside32 = (unsigned*)(ws + off);  off += (size_t)NB * NA * sizeof(unsigned);
    int*      bestg    = (int*)(ws + off);

    const size_t BA = (size_t)NB * NA;
    float* out_sum = out + BA * 7;

    dim3 gA((NA + 255) / 256, NB);
    phaseA<<<gA, 256, 0, stream>>>(preds, gt_bboxes, gt_classes, anchor_points,
                                   align_ws, mask32, inside32, bestg, out_sum);

    const int nWaves = NB * NG;             // 2048 waves, 4 per block
    phaseB<<<nWaves / 4, 256, 0, stream>>>(align_ws, mask32);

    phaseC<<<(int)((BA + 255) / 256), 256, 0, stream>>>(gt_bboxes, gt_classes, align_ws,
                                                        mask32, inside32, bestg, out);
}

// Round 2
// 475.582 us; speedup vs baseline: 1.1924x; 1.1924x over previous
//
#include <hip/hip_runtime.h>
#include <cfloat>
#include <cstdint>

// Problem constants (YOLOv8 640x640 head)
#define NB 64
#define NG 32
#define NC 80
#define NA 8400
#define KTOP 13

// ---------------------------------------------------------------------------
// Phase A: per (b,a) -> decode pred box, softmax, IoU vs all 32 GTs, align
// Writes: align (B,G,A) fp32, inside32 (B,A), bestg (B,A), zeros mask32 (B,A)
// ---------------------------------------------------------------------------
__global__ __launch_bounds__(256) void phaseA(
    const float* __restrict__ preds,          // (B, 84, A)
    const float* __restrict__ gt_bboxes,      // (B, G, 4) xyxy
    const int*   __restrict__ gt_classes,     // (B, G)
    const float* __restrict__ anchor_points,  // (A, 2)
    float*       __restrict__ align,          // (B,G,A)
    unsigned*    __restrict__ mask32,         // (B,A) topk scatter (zeroed here)
    unsigned*    __restrict__ inside32,       // (B,A)
    int*         __restrict__ bestg,          // (B,A)
    float*       __restrict__ out_sum)        // scalar, zeroed here
{
    __shared__ float sx1[NG], sy1[NG], sx2[NG], sy2[NG], sarea[NG];
    __shared__ int   scls[NG];

    const int tid = threadIdx.x;
    const int b   = blockIdx.y;
    const int a   = blockIdx.x * 256 + tid;

    if (tid < NG) {
        const float* gb = gt_bboxes + ((size_t)b * NG + tid) * 4;
        float x1 = gb[0], y1 = gb[1], x2 = gb[2], y2 = gb[3];
        sx1[tid] = x1; sy1[tid] = y1; sx2[tid] = x2; sy2[tid] = y2;
        sarea[tid] = (x2 - x1) * (y2 - y1);
        scls[tid]  = gt_classes[b * NG + tid];
    }
    if (b == 0 && a == 0) out_sum[0] = 0.0f;
    __syncthreads();
    if (a >= NA) return;

    const float ax = anchor_points[a * 2 + 0];
    const float ay = anchor_points[a * 2 + 1];

    const float* db = preds + (size_t)b * (4 + NC) * NA + a;  // dist base
    const float l  = db[0];
    const float t  = db[(size_t)1 * NA];
    const float r  = db[(size_t)2 * NA];
    const float bo = db[(size_t)3 * NA];
    const float x1 = ax - l, y1 = ay - t, x2 = ax + r, y2 = ay + bo;
    const float area_a = (x2 - x1) * (y2 - y1);

    // softmax over 80 classes: max pass, then sum-exp pass
    const float* cb = db + (size_t)4 * NA;
    float mx = -FLT_MAX;
#pragma unroll 4
    for (int c = 0; c < NC; ++c) mx = fmaxf(mx, cb[(size_t)c * NA]);
    float denom = 0.0f;
#pragma unroll 4
    for (int c = 0; c < NC; ++c) denom += __expf(cb[(size_t)c * NA] - mx);
    const float rdenom = 1.0f / denom;

    unsigned inside = 0u;
    int   bg   = 0;
    float biou = -1.0f;   // strict > keeps first max (jnp.argmax semantics)

    float* arow = align + ((size_t)b * NG) * NA + a;
    for (int g = 0; g < NG; ++g) {
        const float bx1 = sx1[g], by1 = sy1[g], bx2 = sx2[g], by2 = sy2[g];
        const float ltx = fmaxf(x1, bx1), lty = fmaxf(y1, by1);
        const float rbx = fminf(x2, bx2), rby = fminf(y2, by2);
        const float w = fmaxf(rbx - ltx, 0.0f);
        const float h = fmaxf(rby - lty, 0.0f);
        const float inter = w * h;
        const float iou = inter / (area_a + sarea[g] - inter + 1e-7f);
        if (iou > biou) { biou = iou; bg = g; }
        const float cv = __expf(cb[(size_t)scls[g] * NA] - mx) * rdenom;
        const float al = sqrtf(fmaxf(iou, 1e-12f)) * sqrtf(fmaxf(cv, 1e-12f));
        arow[(size_t)g * NA] = al;
        const float dmin = fminf(fminf(ax - bx1, ay - by1), fminf(bx2 - ax, by2 - ay));
        if (dmin > 1e-9f) inside |= (1u << g);
    }

    const int i = b * NA + a;
    mask32[i]   = 0u;
    inside32[i] = inside;
    bestg[i]    = bg;
}

// ---------------------------------------------------------------------------
// Phase B: one 256-thread block (4 waves) per (b,g) row: top-13 over A anchors
// lane-local top-13 -> wave butterfly-argmax top-13 -> LDS 52-candidate merge
// Scatter: atomicOr bit g into mask32[b, winner_anchor]
// ---------------------------------------------------------------------------
__global__ __launch_bounds__(256) void phaseB(
    const float* __restrict__ align,   // (B,G,A)
    unsigned*    __restrict__ mask32)  // (B,A)
{
    const int w    = blockIdx.x;        // 0 .. B*G-1
    const int b    = w >> 5;
    const int g    = w & 31;
    const int tid  = threadIdx.x;
    const int lane = tid & 63;
    const int wid  = tid >> 6;

    const float* row = align + (size_t)w * NA;

    float v[KTOP];
    int   id[KTOP];
#pragma unroll
    for (int j = 0; j < KTOP; ++j) { v[j] = -FLT_MAX; id[j] = 0x7FFFFFFF; }

    // lane-local stable top-13 of ~33 strided elements (ascending index order;
    // strict > on shift keeps the earlier index on ties -> stable)
    for (int a = tid; a < NA; a += 256) {
        const float x = row[a];
        if (x > v[KTOP - 1]) {
            int j = KTOP - 1;
            while (j > 0 && v[j - 1] < x) { v[j] = v[j - 1]; id[j] = id[j - 1]; --j; }
            v[j] = x; id[j] = a;
        }
    }

    // wave-level merge: 13 rounds of butterfly argmax (tie-break smaller index)
    __shared__ float lv[4][KTOP];
    __shared__ int   li[4][KTOP];
    int p = 0;
    for (int r = 0; r < KTOP; ++r) {
        const float cv = (p < KTOP) ? v[p]  : -FLT_MAX;
        const int   ci = (p < KTOP) ? id[p] : 0x7FFFFFFF;
        float bv = cv;
        int   bi = ci;
#pragma unroll
        for (int off = 32; off > 0; off >>= 1) {
            const float ov = __shfl_xor(bv, off, 64);
            const int   oi = __shfl_xor(bi, off, 64);
            if (ov > bv || (ov == bv && oi < bi)) { bv = ov; bi = oi; }
        }
        if (ci == bi && p < KTOP) ++p;  // unique anchor ids -> exactly one lane pops
        if (lane == r) { lv[wid][r] = bv; li[wid][r] = bi; }
    }
    __syncthreads();

    // wave 0: merge the 4 waves' 13-lists (52 candidates, one per lane)
    if (wid == 0) {
        float mv = -FLT_MAX;
        int   mi = 0x7FFFFFFF;
        if (lane < 4 * KTOP) { mv = lv[lane / KTOP][lane % KTOP]; mi = li[lane / KTOP][lane % KTOP]; }
        bool used = false;
        for (int r = 0; r < KTOP; ++r) {
            const float cv = used ? -FLT_MAX  : mv;
            const int   ci = used ? 0x7FFFFFFF : mi;
            float bv = cv;
            int   bi = ci;
#pragma unroll
            for (int off = 32; off > 0; off >>= 1) {
                const float ov = __shfl_xor(bv, off, 64);
                const int   oi = __shfl_xor(bi, off, 64);
                if (ov > bv || (ov == bv && oi < bi)) { bv = ov; bi = oi; }
            }
            if (ci == bi) used = true;
            if (lane == 0) atomicOr(&mask32[b * NA + bi], 1u << g);
        }
    }
}

// ---------------------------------------------------------------------------
// Phase C: per (b,a) resolve assignment and write all outputs (as float)
// out layout: tb (B,A,4) | tc (B,A) | ts (B,A) | fg (B,A) | fg_sum (1)
// ---------------------------------------------------------------------------
__global__ __launch_bounds__(256) void phaseC(
    const float*    __restrict__ gt_bboxes,
    const int*      __restrict__ gt_classes,
    const float*    __restrict__ align,     // (B,G,A)
    const unsigned* __restrict__ mask32,
    const unsigned* __restrict__ inside32,
    const int*      __restrict__ bestg,
    float*          __restrict__ out)
{
    __shared__ float ssum[4];
    const int tid = threadIdx.x;
    const int i = blockIdx.x * 256 + tid;   // grid is exact: 2100*256 == NB*NA
    const int b = i / NA;
    const int a = i - b * NA;

    const unsigned m = mask32[i] & inside32[i];
    const int cnt = __popc(m);

    bool fg;
    int  tgt;
    if (cnt > 1)      { tgt = bestg[i];      fg = true;  }
    else if (cnt == 1){ tgt = __ffs(m) - 1;  fg = true;  }
    else              { tgt = 0;             fg = false; }

    const float f = fg ? 1.0f : 0.0f;
    const float* gb = gt_bboxes + ((size_t)b * NG + tgt) * 4;

    float* tb = out + (size_t)i * 4;
    tb[0] = gb[0] * f;
    tb[1] = gb[1] * f;
    tb[2] = gb[2] * f;
    tb[3] = gb[3] * f;

    const size_t BA = (size_t)NB * NA;
    out[BA * 4 + i] = fg ? (float)gt_classes[b * NG + tgt] : 0.0f;
    out[BA * 5 + i] = fg ? align[((size_t)b * NG + tgt) * NA + a] : 0.0f;
    out[BA * 6 + i] = f;

    // fg.sum(): ballot per wave -> LDS -> one atomic per block (exact fp32 ints)
    const unsigned long long ball = __ballot(fg);
    if ((tid & 63) == 0) ssum[tid >> 6] = (float)__popcll(ball);
    __syncthreads();
    if (tid == 0)
        atomicAdd(&out[BA * 7], ssum[0] + ssum[1] + ssum[2] + ssum[3]);
}

// ---------------------------------------------------------------------------
extern "C" void kernel_launch(void* const* d_in, const int* in_sizes, int n_in,
                              void* d_out, int out_size, void* d_ws, size_t ws_size,
                              hipStream_t stream) {
    const float* preds         = (const float*)d_in[0];
    const float* gt_bboxes     = (const float*)d_in[1];
    const int*   gt_classes    = (const int*)  d_in[2];
    const float* anchor_points = (const float*)d_in[3];
    // d_in[4] stride_tensor: unused by the reference math

    float* out = (float*)d_out;

    // workspace carve-up: align (B,G,A) fp32 + 3x (B,A) u32
    char* ws = (char*)d_ws;
    float*    align_ws = (float*)ws;
    size_t    off = (size_t)NB * NG * NA * sizeof(float);
    unsigned* mask32   = (unsigned*)(ws + off);  off += (size_t)NB * NA * sizeof(unsigned);
    unsigned* inside32 = (unsigned*)(ws + off);  off += (size_t)NB * NA * sizeof(unsigned);
    int*      bestg    = (int*)(ws + off);

    const size_t BA = (size_t)NB * NA;
    float* out_sum = out + BA * 7;
    (void)out_sum;

    dim3 gA((NA + 255) / 256, NB);
    phaseA<<<gA, 256, 0, stream>>>(preds, gt_bboxes, gt_classes, anchor_points,
                                   align_ws, mask32, inside32, bestg, out + BA * 7);

    phaseB<<<NB * NG, 256, 0, stream>>>(align_ws, mask32);

    phaseC<<<(int)(BA / 256), 256, 0, stream>>>(gt_bboxes, gt_classes, align_ws,
                                                mask32, inside32, bestg, out);
}